// Round 6
// baseline (106.812 us; speedup 1.0000x reference)
//
#include <hip/hip_runtime.h>
#include <math.h>

#define EPSF 1e-6f

typedef __attribute__((ext_vector_type(8))) short bf16x8;   // 8 bf16 = 4 VGPR (MFMA A/B frag)
typedef __attribute__((ext_vector_type(4))) float f32x4;    // MFMA C/D frag
typedef __attribute__((ext_vector_type(4))) unsigned short u16x4;
typedef __attribute__((ext_vector_type(8))) unsigned short u16x8;

constexpr int TT = 256, MT = 2000, NP = 7200;

static __device__ __forceinline__ unsigned short f2bf(float f) {
    unsigned int u = __float_as_uint(f);
    u += 0x7FFFu + ((u >> 16) & 1u);
    return (unsigned short)(u >> 16);
}
static __device__ __forceinline__ float frcp(float x) { return __builtin_amdgcn_rcpf(x); }

// Async global->LDS, 16B per lane. LDS dest is wave-uniform base (HW adds lane*16).
static __device__ __forceinline__ void gload_lds16(const unsigned short* g, unsigned short* l) {
    __builtin_amdgcn_global_load_lds(
        (const __attribute__((address_space(1))) unsigned int*)(g),
        (__attribute__((address_space(3))) unsigned int*)(l),
        16, 0, 0);
}

// ---------------- Kernel 1: fused prep (unchanged) ----------------
__global__ __launch_bounds__(256) void prep_kernel(const float* __restrict__ logits,
                                                   const float* __restrict__ lab,
                                                   unsigned short* __restrict__ probs,
                                                   unsigned short* __restrict__ nlab) {
    int b = blockIdx.x;
    if (b < 900) {
        int i = (b * 256 + threadIdx.x) * 8;
        float4 x0 = *reinterpret_cast<const float4*>(logits + i);
        float4 x1 = *reinterpret_cast<const float4*>(logits + i + 4);
        float v[8] = {x0.x, x0.y, x0.z, x0.w, x1.x, x1.y, x1.z, x1.w};
        u16x8 o;
#pragma unroll
        for (int j = 0; j < 8; ++j) {
            float s = frcp(1.0f + __expf(-v[j]));
            s = fminf(fmaxf(s, EPSF), 1.0f - EPSF);
            o[j] = f2bf(s);
        }
        *reinterpret_cast<u16x8*>(probs + i) = o;
    } else {
        int wave = threadIdx.x >> 6;
        int lane = threadIdx.x & 63;
        int m = (b - 900) * 4 + wave;               // [0,2000)
        float4 v = reinterpret_cast<const float4*>(lab)[m * (TT / 4) + lane];
        float s = v.x + v.y + v.z + v.w;
#pragma unroll
        for (int off = 32; off > 0; off >>= 1) s += __shfl_down(s, off);
        float inv = frcp(__shfl(s, 0) + EPSF);
        u16x4 o;
        o[0] = f2bf(v.x * inv); o[1] = f2bf(v.y * inv);
        o[2] = f2bf(v.z * inv); o[3] = f2bf(v.w * inv);
        *reinterpret_cast<u16x4*>(nlab + m * TT + lane * 4) = o;
    }
}

// -------- Kernel 2: ZERO-BARRIER per-wave 32x32 tiles, private LDS slices --------
// Ledger R0-R5: every barrier-coupled LDS structure sits at 35-46us; implied
// per-block latency ~32K cy >> the ~4K cy critical path => co-resident blocks
// are NOT overlapping (barrier lockstep couples all waves to the slowest
// stage). Fix: one wave = one 32x32 tile, staged into a PRIVATE 8KB LDS slice
// via gl_lds; vmcnt is per-wave state, so completion needs NO __syncthreads.
// 20 independent instruction streams per CU (5 blocks x 4 waves), free-running.
// K in 4 chunks of 64: {8 gl_lds -> vmcnt(0) -> 8 ds_read_b128 + 8 MFMA}.
// lgkmcnt(0) before re-staging the private buffer (reads must land first).
// Both-sides XOR swizzle (rule #21): source col ^((lane&7)^(lane>>3))<<4,
// read col ^((fr&7)<<4) -- same involution on each 128B LDS row.
constexpr int TN = 225, TM = 63;                    // 32-row / 32-col tiles
constexpr int NBLK = 3544;                          // ceil(225*63/4) ; 8*443

__global__ __launch_bounds__(256, 5) void cost_mfma_kernel(
    const unsigned short* __restrict__ A,   // probs bf16 [NP][TT]
    const unsigned short* __restrict__ B,   // nlab  bf16 [MT][TT]
    const float* __restrict__ pbox,         // [NP][4] cxcywh
    const float* __restrict__ tbox,         // [MT][4] cxcywh
    float* __restrict__ out)                // [NP][MT] fp32
{
    __shared__ __align__(16) unsigned short S[4][64 * 64];  // 4 waves x 8KB slices

    // XCD slab swizzle (bijective: 3544 = 8*443): XCD c gets contiguous l-slab
    // -> ~0.46MB A-slab + 1MB B in its L2.
    int n = blockIdx.x;
    int l = (n & 7) * 443 + (n >> 3);

    const int tid = threadIdx.x;
    const int lane = tid & 63, wave = tid >> 6;
    const int t = l * 4 + wave;                     // wave-tile id, [0, 14176)
    const int tn = t / TM, tm = t - tn * TM;        // consecutive t -> same tn: 4
    const int n0 = tn * 32, m0 = tm * 32;           // waves share A-panel (L1-hot)

    const int fr = lane & 15, quad = lane >> 4;     // fragment row / k-quad
    const int row_off = lane >> 3;                  // 0..7 (8 rows per 1KB issue)
    const int cs = (((lane & 7) ^ row_off) << 4);   // swizzled source byte col

    // Clamped global rows for the 4 issues per plane (same rows every chunk).
    int gn[4], gm[4];
#pragma unroll
    for (int i = 0; i < 4; ++i) {
        int r = i * 8 + row_off;
        int a = n0 + r; gn[i] = a > NP - 1 ? NP - 1 : a;
        int b = m0 + r; gm[i] = b > MT - 1 ? MT - 1 : b;
    }

    unsigned short* Sw = S[wave];
    const char* base = reinterpret_cast<const char*>(Sw);
    const int xs = (fr & 7) << 4;                   // read-side swizzle
    f32x4 acc[2][2] = {};

#pragma unroll
    for (int c = 0; c < 4; ++c) {                   // K = 4 chunks of 64
        // ---- stage chunk c into the private slice (A rows 0-31, B rows 32-63) ----
#pragma unroll
        for (int i = 0; i < 4; ++i)
            gload_lds16(A + gn[i] * TT + c * 64 + (cs >> 1), Sw + (i * 8) * 64);
#pragma unroll
        for (int i = 0; i < 4; ++i)
            gload_lds16(B + gm[i] * TT + c * 64 + (cs >> 1), Sw + ((32 + i * 8)) * 64);
        asm volatile("s_waitcnt vmcnt(0)" ::: "memory");   // own-wave loads only
        __builtin_amdgcn_sched_barrier(0);

        // ---- 2 k-steps x 4 MFMA on the chunk ----
#pragma unroll
        for (int k2 = 0; k2 < 2; ++k2) {
            int cb = (k2 * 64 + quad * 16) ^ xs;    // swizzled byte col in 128B row
            bf16x8 a0 = *reinterpret_cast<const bf16x8*>(base + (fr) * 128 + cb);
            bf16x8 a1 = *reinterpret_cast<const bf16x8*>(base + (16 + fr) * 128 + cb);
            bf16x8 b0 = *reinterpret_cast<const bf16x8*>(base + (32 + fr) * 128 + cb);
            bf16x8 b1 = *reinterpret_cast<const bf16x8*>(base + (48 + fr) * 128 + cb);
            acc[0][0] = __builtin_amdgcn_mfma_f32_16x16x32_bf16(a0, b0, acc[0][0], 0, 0, 0);
            acc[0][1] = __builtin_amdgcn_mfma_f32_16x16x32_bf16(a0, b1, acc[0][1], 0, 0, 0);
            acc[1][0] = __builtin_amdgcn_mfma_f32_16x16x32_bf16(a1, b0, acc[1][0], 0, 0, 0);
            acc[1][1] = __builtin_amdgcn_mfma_f32_16x16x32_bf16(a1, b1, acc[1][1], 0, 0, 0);
        }
        if (c < 3) {   // reads must have landed in VGPRs before overwrite
            asm volatile("s_waitcnt lgkmcnt(0)" ::: "memory");
            __builtin_amdgcn_sched_barrier(0);
        }
    }

    // -------- epilogue: box costs + stores (per-wave 32x32 tile) --------
    float bcx[2], bcy[2], bww[2], bhh[2], bx1[2], by1[2], bx2[2], by2[2], areaB[2];
    int mj[2]; bool mv[2];
#pragma unroll
    for (int tj = 0; tj < 2; ++tj) {
        int gm2 = m0 + tj * 16 + fr;
        mv[tj] = gm2 < MT; mj[tj] = gm2;
        int g = mv[tj] ? gm2 : MT - 1;
        float4 b = *reinterpret_cast<const float4*>(&tbox[g * 4]);
        bcx[tj] = b.x; bcy[tj] = b.y; bww[tj] = b.z; bhh[tj] = b.w;
        bx1[tj] = b.x - 0.5f * b.z; by1[tj] = b.y - 0.5f * b.w;
        bx2[tj] = b.x + 0.5f * b.z; by2[tj] = b.y + 0.5f * b.w;
        areaB[tj] = (bx2[tj] - bx1[tj]) * (by2[tj] - by1[tj]);
    }

#pragma unroll
    for (int ti = 0; ti < 2; ++ti) {
#pragma unroll
        for (int r = 0; r < 4; ++r) {
            int p = n0 + ti * 16 + quad * 4 + r;    // C/D: row = quad*4 + reg
            if (p >= NP) continue;
            float4 pb4 = *reinterpret_cast<const float4*>(&pbox[p * 4]);
            float ax1 = pb4.x - 0.5f * pb4.z, ay1 = pb4.y - 0.5f * pb4.w;
            float ax2 = pb4.x + 0.5f * pb4.z, ay2 = pb4.y + 0.5f * pb4.w;
            float areaA = (ax2 - ax1) * (ay2 - ay1);
#pragma unroll
            for (int tj = 0; tj < 2; ++tj) {
                if (!mv[tj]) continue;
                float l1 = fabsf(pb4.x - bcx[tj]) + fabsf(pb4.y - bcy[tj]) +
                           fabsf(pb4.z - bww[tj]) + fabsf(pb4.w - bhh[tj]);
                float ltx = fmaxf(ax1, bx1[tj]), lty = fmaxf(ay1, by1[tj]);
                float rbx = fminf(ax2, bx2[tj]), rby = fminf(ay2, by2[tj]);
                float iw = fmaxf(rbx - ltx, 0.0f), ih = fmaxf(rby - lty, 0.0f);
                float inter = iw * ih;
                float uni = areaA + areaB[tj] - inter;
                float iou = inter * frcp(uni + EPSF);
                float ex1 = fminf(ax1, bx1[tj]), ey1 = fminf(ay1, by1[tj]);
                float ex2 = fmaxf(ax2, bx2[tj]), ey2 = fmaxf(ay2, by2[tj]);
                float ew = fmaxf(ex2 - ex1, 0.0f), eh = fmaxf(ey2 - ey1, 0.0f);
                float areaE = ew * eh;
                float giou = iou - (areaE - uni) * frcp(areaE + EPSF);
                float res = 5.0f * l1 - acc[ti][tj][r] - 2.0f * fmaxf(giou, -1.0f);
                out[p * MT + mj[tj]] = res;
            }
        }
    }
}

extern "C" void kernel_launch(void* const* d_in, const int* in_sizes, int n_in,
                              void* d_out, int out_size, void* d_ws, size_t ws_size,
                              hipStream_t stream) {
    const float* pred_logits = (const float*)d_in[0];  // [8,900,256]
    const float* pred_boxes  = (const float*)d_in[1];  // [8,900,4]
    const float* tgt_boxes   = (const float*)d_in[2];  // [2000,4]
    const float* tgt_labels  = (const float*)d_in[3];  // [2000,256]
    float* out = (float*)d_out;                        // [7200,2000]

    unsigned short* probs = (unsigned short*)d_ws;     // 7200*256 bf16 (3.7 MB)
    unsigned short* nlab  = probs + NP * TT;           // 2000*256 bf16 (1.0 MB)

    prep_kernel<<<900 + 500, 256, 0, stream>>>(pred_logits, tgt_labels, probs, nlab);

    cost_mfma_kernel<<<NBLK, 256, 0, stream>>>(probs, nlab, pred_boxes, tgt_boxes, out);
}